// Round 5
// baseline (176.890 us; speedup 1.0000x reference)
//
#include <hip/hip_runtime.h>
#include <hip/hip_fp16.h>
#include <math.h>

#define DFEAT 128
typedef unsigned long long u64;
typedef unsigned int u32;
#define END32 0xFFFFFFFFu

// Fused kernel, split by block range:
//  - blocks [0, eluBlocks): emb2[i] = fp16( 2*elu(x[i]*w[i%D]) ), plus zeros row N.
//  - blocks [eluBlocks, ..): linked-list binning, 4 edges per thread:
//      head32[d] <- atomicExch(e);  nxt[e] = (src[e]<<32) | old_head   (coalesced u64 stream)
//    4 independent atomicExch per thread keeps enough atomics in flight to
//    cover the ~700-cycle memory-side round trip.
__global__ void fused_elu_bin_kernel(const float* __restrict__ x,
                                     const float* __restrict__ w,
                                     __half* __restrict__ emb2,
                                     int total4, int total4ext,
                                     const int* __restrict__ src,
                                     const int* __restrict__ dst, int E,
                                     u32* __restrict__ head,
                                     u64* __restrict__ nxt,
                                     int eluBlocks, int N) {
    if ((int)blockIdx.x < eluBlocks) {
        int idx = blockIdx.x * blockDim.x + threadIdx.x;   // group of 4 elements
        if (idx >= total4ext) return;
        uint2 pk = make_uint2(0u, 0u);                      // zeros row for idx>=total4
        if (idx < total4) {
            float4 xv = ((const float4*)x)[idx];
            float4 wv = ((const float4*)w)[idx & (DFEAT / 4 - 1)];
            float a, r0, r1, r2, r3;
            a = xv.x * wv.x; r0 = 2.0f * (a > 0.0f ? a : (__expf(a) - 1.0f));
            a = xv.y * wv.y; r1 = 2.0f * (a > 0.0f ? a : (__expf(a) - 1.0f));
            a = xv.z * wv.z; r2 = 2.0f * (a > 0.0f ? a : (__expf(a) - 1.0f));
            a = xv.w * wv.w; r3 = 2.0f * (a > 0.0f ? a : (__expf(a) - 1.0f));
            __half2 h01 = __floats2half2_rn(r0, r1);
            __half2 h23 = __floats2half2_rn(r2, r3);
            pk.x = *(u32*)&h01;
            pk.y = *(u32*)&h23;
        }
        ((uint2*)emb2)[idx] = pk;
    } else {
        int i = (blockIdx.x - eluBlocks) * blockDim.x + threadIdx.x;  // 4-edge group
        int base = i * 4;
        if (base >= E) return;
        if (i == 0) nxt[E] = ((u64)(u32)N << 32) | END32;  // sentinel: zeros row, stays ended
        if (base + 3 < E) {
            int4 s4 = ((const int4*)src)[i];
            int4 d4 = ((const int4*)dst)[i];
            u32 o0 = atomicExch(&head[d4.x], (u32)(base + 0));
            u32 o1 = atomicExch(&head[d4.y], (u32)(base + 1));
            u32 o2 = atomicExch(&head[d4.z], (u32)(base + 2));
            u32 o3 = atomicExch(&head[d4.w], (u32)(base + 3));
            nxt[base + 0] = ((u64)(u32)s4.x << 32) | o0;
            nxt[base + 1] = ((u64)(u32)s4.y << 32) | o1;
            nxt[base + 2] = ((u64)(u32)s4.z << 32) | o2;
            nxt[base + 3] = ((u64)(u32)s4.w << 32) | o3;
        } else {
            for (int e = base; e < E; ++e) {
                u32 o = atomicExch(&head[dst[e]], (u32)e);
                nxt[e] = ((u64)(u32)src[e] << 32) | o;
            }
        }
    }
}

// One wave per 4 destination nodes; lane owns 2 fp16 columns (one u32).
// State per chain: current edge e + prefetched v = nxt[e]. The emb row load
// comes from v (off the critical path); only the nxt chain is serial, and
// 4 chains per wave keep 4 of them in flight. Sentinel chains read the zeros
// row and stay at END32; loop exits when AND of all e == END32.
__global__ void gather_ll_kernel(const u32* __restrict__ embu,   // (N+1)*64 u32
                                 const u32* __restrict__ head,
                                 const u64* __restrict__ nxt,
                                 float* __restrict__ out, int N, int E) {
    int wid = (blockIdx.x * blockDim.x + threadIdx.x) >> 6;
    int lane = threadIdx.x & 63;
    int nA = wid * 4;
    if (nA >= N) return;
    int nB = nA + 1, nC = nA + 2, nD = nA + 3;
    const u32 uE = (u32)E;
    u32 eA = head[nA];
    u32 eB = (nB < N) ? head[nB] : END32;
    u32 eC = (nC < N) ? head[nC] : END32;
    u32 eD = (nD < N) ? head[nD] : END32;
    u64 vA = nxt[min(eA, uE)];
    u64 vB = nxt[min(eB, uE)];
    u64 vC = nxt[min(eC, uE)];
    u64 vD = nxt[min(eD, uE)];
    float2 accA = make_float2(0.0f, 0.0f);
    float2 accB = make_float2(0.0f, 0.0f);
    float2 accC = make_float2(0.0f, 0.0f);
    float2 accD = make_float2(0.0f, 0.0f);
    while ((eA & eB & eC & eD) != END32) {
        u32 hA = embu[(u32)(vA >> 32) * 64u + (u32)lane];
        u32 hB = embu[(u32)(vB >> 32) * 64u + (u32)lane];
        u32 hC = embu[(u32)(vC >> 32) * 64u + (u32)lane];
        u32 hD = embu[(u32)(vD >> 32) * 64u + (u32)lane];
        eA = (u32)vA; eB = (u32)vB; eC = (u32)vC; eD = (u32)vD;
        vA = nxt[min(eA, uE)];
        vB = nxt[min(eB, uE)];
        vC = nxt[min(eC, uE)];
        vD = nxt[min(eD, uE)];
        float2 fA = __half22float2(*(__half2*)&hA);
        float2 fB = __half22float2(*(__half2*)&hB);
        float2 fC = __half22float2(*(__half2*)&hC);
        float2 fD = __half22float2(*(__half2*)&hD);
        accA.x += fA.x; accA.y += fA.y;
        accB.x += fB.x; accB.y += fB.y;
        accC.x += fC.x; accC.y += fC.y;
        accD.x += fD.x; accD.y += fD.y;
    }
    ((float2*)out)[(u32)nA * 64u + (u32)lane] = accA;
    if (nB < N) ((float2*)out)[(u32)nB * 64u + (u32)lane] = accB;
    if (nC < N) ((float2*)out)[(u32)nC * 64u + (u32)lane] = accC;
    if (nD < N) ((float2*)out)[(u32)nD * 64u + (u32)lane] = accD;
}

// Fallback if ws too small: fuse elu into gather, fp32 atomic scatter.
__global__ void scatter_fused_kernel(const float* __restrict__ x,
                                     const float* __restrict__ w,
                                     const int* __restrict__ src,
                                     const int* __restrict__ dst,
                                     float* __restrict__ out, int E) {
    int t = blockIdx.x * blockDim.x + threadIdx.x;
    int edge = t >> 5;
    int lane = t & 31;
    if (edge >= E) return;
    int s = src[edge];
    int d = dst[edge];
    float4 xv = ((const float4*)(x + (size_t)s * DFEAT))[lane];
    float4 wv = ((const float4*)w)[lane];
    float4 v;
    float a;
    a = xv.x * wv.x; v.x = 2.0f * (a > 0.0f ? a : (__expf(a) - 1.0f));
    a = xv.y * wv.y; v.y = 2.0f * (a > 0.0f ? a : (__expf(a) - 1.0f));
    a = xv.z * wv.z; v.z = 2.0f * (a > 0.0f ? a : (__expf(a) - 1.0f));
    a = xv.w * wv.w; v.w = 2.0f * (a > 0.0f ? a : (__expf(a) - 1.0f));
    float* op = out + (size_t)d * DFEAT + lane * 4;
    unsafeAtomicAdd(op + 0, v.x);
    unsafeAtomicAdd(op + 1, v.y);
    unsafeAtomicAdd(op + 2, v.z);
    unsafeAtomicAdd(op + 3, v.w);
}

extern "C" void kernel_launch(void* const* d_in, const int* in_sizes, int n_in,
                              void* d_out, int out_size, void* d_ws, size_t ws_size,
                              hipStream_t stream) {
    const float* x   = (const float*)d_in[0];   // graph_embedding [N, 128]
    const float* w   = (const float*)d_in[1];   // weight [1, 128]
    const int*   src = (const int*)d_in[3];     // src [E]
    const int*   dst = (const int*)d_in[4];     // dst [E]
    float* out = (float*)d_out;

    const int ND = in_sizes[0];          // N * 128
    const int N  = ND / DFEAT;           // 50000
    const int E  = in_sizes[2];          // 800000

    size_t emb_bytes  = (((size_t)(N + 1) * DFEAT) * sizeof(__half) + 15) & ~(size_t)15;
    size_t head_bytes = ((size_t)N * sizeof(u32) + 15) & ~(size_t)15;
    size_t nxt_bytes  = (size_t)(E + 1) * sizeof(u64);
    size_t total = emb_bytes + head_bytes + nxt_bytes;

    if (ws_size >= total) {
        char* p = (char*)d_ws;
        __half* emb2 = (__half*)p;  p += emb_bytes;
        u32*    head = (u32*)p;     p += head_bytes;
        u64*    nxt  = (u64*)p;

        // sentinel-fill heads (0xFF bytes == END32)
        hipMemsetAsync(head, 0xFF, (size_t)N * sizeof(u32), stream);

        int total4    = ND / 4;                    // real rows
        int total4ext = total4 + DFEAT / 4;        // + zeros row N
        int eluBlocks = (total4ext + 255) / 256;
        int binGroups = (E + 3) / 4;               // 4 edges per thread
        int binBlocks = (binGroups + 255) / 256;
        fused_elu_bin_kernel<<<eluBlocks + binBlocks, 256, 0, stream>>>(
            x, w, emb2, total4, total4ext, src, dst, E, head, nxt, eluBlocks, N);

        long long waves = (N + 3) / 4;
        long long thr = waves * 64;
        gather_ll_kernel<<<(int)((thr + 255) / 256), 256, 0, stream>>>(
            (const u32*)emb2, head, nxt, out, N, E);
    } else {
        hipMemsetAsync(d_out, 0, (size_t)out_size * sizeof(float), stream);
        long long threads = (long long)E * 32;
        scatter_fused_kernel<<<(int)((threads + 255) / 256), 256, 0, stream>>>(x, w, src, dst, out, E);
    }
}